// Round 3
// baseline (398.913 us; speedup 1.0000x reference)
//
#include <hip/hip_runtime.h>
#include <cfloat>

// Problem constants
#define T_TOTAL 32768   // 32*32*32 spatial positions
#define DIM 64          // embedding dim
#define KCODES 1024     // num embeddings

// d_out flat layout (fp32 elements), reference return order:
//   quantized_out [32,64,32,32] = 2097152
//   loss (1), perplexity (1)
//   encodings [32768,1024] = 33554432
//   distances [32768,1024] = 33554432
static constexpr long long OFF_Q    = 0;
static constexpr long long OFF_LOSS = 2097152;
static constexpr long long OFF_PERP = 2097153;
static constexpr long long OFF_ENC  = 2097154;            // even, but NOT 16B aligned -> float2 max
static constexpr long long OFF_DIST = 2097154LL + 33554432LL; // even, NOT 16B aligned -> float2 max

// ws layout: [0,4096) int counts[1024]; [4096,8192) float ww[1024];
//            [8192,8196) float lossSum; [12288, 12288+256K) float WT[64][1024]

// ---------------------------------------------------------------------------
// Prep: ||w_k||^2 (blocks 0..255) + W transpose WT[n][k] (blocks 256..319).
__global__ __launch_bounds__(256) void vq_prep_kernel(const float* __restrict__ W,
                                                      float* __restrict__ ww,
                                                      float* __restrict__ WT) {
    const int tid = threadIdx.x;
    if (blockIdx.x < 256) {
        const int lane = tid & 63;
        const int code = blockIdx.x * 4 + (tid >> 6);
        float v = W[code * DIM + lane];
        float s = v * v;
        #pragma unroll
        for (int off = 32; off > 0; off >>= 1)
            s += __shfl_down(s, off, 64);
        if (lane == 0) ww[code] = s;
    } else {
        const int n = blockIdx.x - 256;   // 0..63
        #pragma unroll
        for (int i = 0; i < 4; ++i) {
            int k = i * 256 + tid;
            WT[n * KCODES + k] = W[k * DIM + n];
        }
    }
}

// ---------------------------------------------------------------------------
// Main fused kernel. 1024 blocks x 256 threads; block owns 32 rows.
// Wave w handles rows w*8..w*8+7 (full-wave a-broadcast, dense stores).
// Thread cols (per 512-chunk): ct*2 + j*128 + {0,1}, j=0..3 -> 4x ds_read_b64,
// dist stores are fully dense 512B per wave-instruction.
__global__ __launch_bounds__(256, 4) void vq_main_kernel(const float* __restrict__ lat,
                                                         const float* __restrict__ W,
                                                         const float* __restrict__ ww,
                                                         const float* __restrict__ WT,
                                                         float* __restrict__ out,
                                                         int* __restrict__ counts,
                                                         float* __restrict__ lossSum) {
    __shared__ float xT[64 * 32];      // [n][tl] 8 KB — persistent
    __shared__ float wS[8 * 512];      // [n][k] 16 KB staging; aliased as qS[32][65] later
    __shared__ float xx[32];           // ||x_row||^2
    __shared__ int   selIdx[32];

    const int tid = threadIdx.x;
    const int ct  = tid & 63;          // col thread within wave
    const int rg  = tid >> 6;          // wave id == row group (rows rg*8..rg*8+7)
    const int t0  = blockIdx.x * 32;
    // flat row t -> latent addr b*65536 + n*1024 + (j*32+d); 32-row block stays in one b
    const long long base = (long long)(t0 >> 10) * 65536 + (long long)(t0 & 1023);

    // ---- stage x tile (8 KB): dense global reads, contiguous LDS writes
    #pragma unroll
    for (int i = 0; i < 8; ++i) {
        int e  = i * 256 + tid;        // == n*32 + tl
        int n  = e >> 5;
        int tl = e & 31;
        xT[e] = lat[base + (long long)n * 1024 + tl];
    }
    __syncthreads();
    if (tid < 32) {                    // wave 0 computes ||x||^2 while others stage W
        float s = 0.f;
        #pragma unroll 8
        for (int n = 0; n < 64; ++n) {
            float v = xT[n * 32 + tid];
            s = fmaf(v, v, s);
        }
        xx[tid] = s;                   // visible after next __syncthreads
    }

    float minV[8];
    int   minI[8];
    #pragma unroll
    for (int r = 0; r < 8; ++r) { minV[r] = FLT_MAX; minI[r] = 0; }

    float* __restrict__ distOut = out + OFF_DIST;

    for (int c = 0; c < 2; ++c) {      // 2 chunks of 512 codes
        float acc[8][8];
        #pragma unroll
        for (int r = 0; r < 8; ++r)
            #pragma unroll
            for (int k = 0; k < 8; ++k) acc[r][k] = 0.f;

        for (int sub = 0; sub < 8; ++sub) {   // 8 n-rows per staging phase
            __syncthreads();                  // previous phase done reading wS
            #pragma unroll
            for (int i = 0; i < 4; ++i) {
                int e  = i * 256 + tid;       // [0,1024) float4s
                int n  = e >> 7;              // 0..7
                int k4 = (e & 127) * 4;
                *(float4*)&wS[n * 512 + k4] =
                    *(const float4*)&WT[(sub * 8 + n) * KCODES + c * 512 + k4];
            }
            __syncthreads();

            #pragma unroll
            for (int nn = 0; nn < 8; ++nn) {
                const int ng = sub * 8 + nn;
                float4 a0 = *(const float4*)&xT[ng * 32 + rg * 8];      // full-wave broadcast
                float4 a1 = *(const float4*)&xT[ng * 32 + rg * 8 + 4];
                float2 b0 = *(const float2*)&wS[nn * 512 + ct * 2];     // lane-dense b64
                float2 b1 = *(const float2*)&wS[nn * 512 + ct * 2 + 128];
                float2 b2 = *(const float2*)&wS[nn * 512 + ct * 2 + 256];
                float2 b3 = *(const float2*)&wS[nn * 512 + ct * 2 + 384];
                float ar[8] = {a0.x, a0.y, a0.z, a0.w, a1.x, a1.y, a1.z, a1.w};
                float br[8] = {b0.x, b0.y, b1.x, b1.y, b2.x, b2.y, b3.x, b3.y};
                #pragma unroll
                for (int r = 0; r < 8; ++r)
                    #pragma unroll
                    for (int k = 0; k < 8; ++k)
                        acc[r][k] = fmaf(ar[r], br[k], acc[r][k]);
            }
        }

        // ---- distances + running argmin (strict <, ascending k within thread)
        const int kb = c * 512 + ct * 2;   // thread col base; cols kb + j*128 + {0,1}
        float2 wwv[4];
        #pragma unroll
        for (int j = 0; j < 4; ++j)
            wwv[j] = *(const float2*)&ww[kb + j * 128];
        #pragma unroll
        for (int r = 0; r < 8; ++r) {
            const int row = rg * 8 + r;
            const float xxr = xx[row];
            const long long ro = (long long)(t0 + row) * KCODES + kb;
            #pragma unroll
            for (int j = 0; j < 4; ++j) {
                float d0 = (xxr + wwv[j].x) - 2.f * acc[r][2 * j];
                float d1 = (xxr + wwv[j].y) - 2.f * acc[r][2 * j + 1];
                const int ki = kb + j * 128;
                if (d0 < minV[r]) { minV[r] = d0; minI[r] = ki; }
                if (d1 < minV[r]) { minV[r] = d1; minI[r] = ki + 1; }
                *(float2*)&distOut[ro + j * 128] = make_float2(d0, d1);  // dense 512B/instr
            }
        }
    }

    // ---- per-row argmin across the wave via shuffles (lexicographic (v,i) min)
    #pragma unroll
    for (int r = 0; r < 8; ++r) {
        float v  = minV[r];
        int   i0 = minI[r];
        #pragma unroll
        for (int off = 32; off > 0; off >>= 1) {
            float v2 = __shfl_down(v, off, 64);
            int   i2 = __shfl_down(i0, off, 64);
            if (v2 < v || (v2 == v && i2 < i0)) { v = v2; i0 = i2; }
        }
        if (ct == 0) {
            selIdx[rg * 8 + r] = i0;
            atomicAdd(&counts[i0], 1);
        }
    }
    __syncthreads();

    // ---- gather selected codebook rows into LDS (stride 65 kills conflicts)
    float* qS = wS;  // 32*65 = 2080 floats, fits
    #pragma unroll
    for (int i = 0; i < 8; ++i) {
        int e   = i * 256 + tid;
        int row = e >> 6;
        int n   = e & 63;
        qS[row * 65 + n] = W[selIdx[row] * DIM + n];
    }
    __syncthreads();

    // ---- quantized_out (dense float4) + loss partial
    float ls = 0.f;
    #pragma unroll
    for (int i = 0; i < 2; ++i) {
        int e2  = i * 256 + tid;       // [0,512) float4 slots
        int n   = e2 >> 3;             // 0..63
        int tl0 = (e2 & 7) * 4;
        float q0 = qS[(tl0 + 0) * 65 + n];
        float q1 = qS[(tl0 + 1) * 65 + n];
        float q2 = qS[(tl0 + 2) * 65 + n];
        float q3 = qS[(tl0 + 3) * 65 + n];
        float x0 = xT[n * 32 + tl0 + 0];
        float x1 = xT[n * 32 + tl0 + 1];
        float x2 = xT[n * 32 + tl0 + 2];
        float x3 = xT[n * 32 + tl0 + 3];
        *(float4*)&out[OFF_Q + base + (long long)n * 1024 + tl0] = make_float4(q0, q1, q2, q3);
        float e0 = q0 - x0; ls = fmaf(e0, e0, ls);
        float e1 = q1 - x1; ls = fmaf(e1, e1, ls);
        float e2d = q2 - x2; ls = fmaf(e2d, e2d, ls);
        float e3 = q3 - x3; ls = fmaf(e3, e3, ls);
    }
    #pragma unroll
    for (int off = 32; off > 0; off >>= 1)
        ls += __shfl_down(ls, off, 64);
    if (ct == 0) atomicAdd(lossSum, ls);

    // ---- one-hot encodings: 32 rows x 1024, dense float2 stores
    float* __restrict__ enc = out + OFF_ENC;
    #pragma unroll 4
    for (int i = 0; i < 64; ++i) {
        int e2  = i * 256 + tid;       // [0,16384) float2 slots
        int row = e2 >> 9;             // const per iteration
        int k2  = (e2 & 511) * 2;
        int sel = selIdx[row];
        float2 v;
        v.x = (k2     == sel) ? 1.f : 0.f;
        v.y = (k2 + 1 == sel) ? 1.f : 0.f;
        *(float2*)&enc[(long long)(t0 + row) * KCODES + k2] = v;
    }
}

// ---------------------------------------------------------------------------
// Finalize: perplexity from histogram, loss from accumulated SSE.
__global__ __launch_bounds__(1024) void vq_finalize_kernel(const int* __restrict__ counts,
                                                           const float* __restrict__ lossSum,
                                                           float* __restrict__ out) {
    __shared__ float red[16];
    const int tid = threadIdx.x;
    float p = (float)counts[tid] * (1.0f / 32768.0f);   // exact (pow2 divisor)
    float term = p * logf(p + 1e-10f);
    #pragma unroll
    for (int off = 32; off > 0; off >>= 1)
        term += __shfl_down(term, off, 64);
    if ((tid & 63) == 0) red[tid >> 6] = term;
    __syncthreads();
    if (tid == 0) {
        float s = 0.f;
        #pragma unroll
        for (int i = 0; i < 16; ++i) s += red[i];
        out[OFF_PERP] = expf(-s);
        out[OFF_LOSS] = 0.25f * lossSum[0] * (1.0f / 2097152.0f);  // COMMIT_COST * mean SSE
    }
}

// ---------------------------------------------------------------------------
extern "C" void kernel_launch(void* const* d_in, const int* in_sizes, int n_in,
                              void* d_out, int out_size, void* d_ws, size_t ws_size,
                              hipStream_t stream) {
    (void)in_sizes; (void)n_in; (void)out_size; (void)ws_size;
    const float* lat = (const float*)d_in[0];   // [32,64,32,32]
    const float* W   = (const float*)d_in[1];   // [1024,64]
    float* out = (float*)d_out;

    int*   counts  = (int*)d_ws;
    float* ww      = (float*)((char*)d_ws + 4096);
    float* lossSum = (float*)((char*)d_ws + 8192);
    float* WT      = (float*)((char*)d_ws + 12288);   // 64x1024 fp32 = 256 KB

    // zero counts + lossSum (ww/WT fully overwritten by vq_prep_kernel)
    hipMemsetAsync(d_ws, 0, 8192 + 16, stream);

    vq_prep_kernel<<<320, 256, 0, stream>>>(W, ww, WT);
    vq_main_kernel<<<1024, 256, 0, stream>>>(lat, W, ww, WT, out, counts, lossSum);
    vq_finalize_kernel<<<1, 1024, 0, stream>>>(counts, lossSum, out);
}